// Round 20
// baseline (117.831 us; speedup 1.0000x reference)
//
#include <hip/hip_runtime.h>

typedef __bf16 bf16;
typedef __bf16 bf16x8 __attribute__((ext_vector_type(8), aligned(16)));
typedef float  f32x4  __attribute__((ext_vector_type(4)));
typedef float  f32x2  __attribute__((ext_vector_type(2)));
typedef long   longx2 __attribute__((ext_vector_type(2)));

#define B_ 8
#define T_ 16
#define N_ 2048
#define C_ 512

// ---- helpers ----
__device__ inline void gload_lds16(const void* g, void* l) {
    __builtin_amdgcn_global_load_lds(
        (const __attribute__((address_space(1))) void*)g,
        (__attribute__((address_space(3))) void*)l, 16, 0, 0);
}

__device__ inline unsigned char f32_to_fp8(float v) {
    int p = __builtin_amdgcn_cvt_pk_fp8_f32(v, 0.f, 0, false);
    return (unsigned char)(p & 0xff);
}

__device__ inline void fp8x4_to_f32(unsigned int wd, float* o) {
    f32x2 lo = __builtin_amdgcn_cvt_pk_f32_fp8((int)wd, false);
    f32x2 hi = __builtin_amdgcn_cvt_pk_f32_fp8((int)wd, true);
    o[0] = lo[0]; o[1] = lo[1]; o[2] = hi[0]; o[3] = hi[1];
}

// K-permutation within each 64-block (for b128 frag reads in gemm256w):
// phys(k) = ((k>>3)&3)*16 + ((k>>5)&1)*8 + (k&7)

// Merged prep kernel:
//   [0,2048):    nodes fp32 -> bf16 AND fp8(e4m3, K-permuted within 64-blocks)
//   [2048,2064): out_scene = mean_t vd_s
//   [2064,2320): W1t = W1^T   [2320,2576): W2t = W2^T
//   [2576,2592): qpart[p][c] = sum_{k in 32-slice p} b1[k]*W2[k][c]
//   [2592]:      zero out[:, 512:1024]  (gp region, accumulated by k_gp atomics)
__global__ __launch_bounds__(256) void k_prep(
    const float* __restrict__ vd_s, const float* __restrict__ nodes,
    const float* __restrict__ W1, const float* __restrict__ W2,
    const float* __restrict__ b1,
    float* __restrict__ out, bf16* __restrict__ nodes_bf,
    unsigned char* __restrict__ nodes_f8,
    bf16* __restrict__ W1t, bf16* __restrict__ W2t,
    float* __restrict__ qpart) {
    __shared__ float sh[32 * 33];
    const int bx = blockIdx.x, tid = threadIdx.x;
    if (bx < 2048) {
        size_t i = ((size_t)bx * 256 + tid) * 16;    // 16 channels, i%16==0
        float v[16];
        *(float4*)&v[0]  = *(const float4*)(nodes + i);
        *(float4*)&v[4]  = *(const float4*)(nodes + i + 4);
        *(float4*)&v[8]  = *(const float4*)(nodes + i + 8);
        *(float4*)&v[12] = *(const float4*)(nodes + i + 12);
        bf16x8 b0, b1v;
#pragma unroll
        for (int e = 0; e < 8; ++e) { b0[e] = (bf16)v[e]; b1v[e] = (bf16)v[8 + e]; }
        *(bf16x8*)(nodes_bf + i)     = b0;
        *(bf16x8*)(nodes_bf + i + 8) = b1v;
        unsigned int wds[4];
#pragma unroll
        for (int k = 0; k < 4; ++k) {
            int p = __builtin_amdgcn_cvt_pk_fp8_f32(v[k * 4 + 0], v[k * 4 + 1], 0, false);
            p = __builtin_amdgcn_cvt_pk_fp8_f32(v[k * 4 + 2], v[k * 4 + 3], p, true);
            wds[k] = (unsigned int)p;
        }
        int j = (int)((i >> 4) & 3);
        size_t base = i & ~(size_t)63;
        size_t pa1 = base + (size_t)(((2 * j) & 3) * 16 + (j >> 1) * 8);
        size_t pa2 = base + (size_t)(((2 * j + 1) & 3) * 16 + (j >> 1) * 8);
        uint2 u1; u1.x = wds[0]; u1.y = wds[1];
        uint2 u2; u2.x = wds[2]; u2.y = wds[3];
        *(uint2*)(nodes_f8 + pa1) = u1;
        *(uint2*)(nodes_f8 + pa2) = u2;
    } else if (bx < 2064) {
        int gt = (bx - 2048) * 256 + tid;
        int b = gt >> 9, c = gt & 511;
        float s = 0.f;
#pragma unroll
        for (int t = 0; t < T_; ++t) s += vd_s[(size_t)b * T_ * C_ + t * C_ + c];
        out[b * 2 * C_ + c] = s * (1.0f / T_);
    } else if (bx < 2576) {
        const float* W = (bx < 2320) ? W1 : W2;
        bf16* Wt = (bx < 2320) ? W1t : W2t;
        int idx = (bx < 2320) ? bx - 2064 : bx - 2320;
        int bxx = (idx & 15) * 32, byy = (idx >> 4) * 32;
        int tx = tid & 31, ty = tid >> 5;
#pragma unroll
        for (int r = 0; r < 32; r += 8)
            sh[(ty + r) * 33 + tx] = W[(size_t)(byy + ty + r) * C_ + bxx + tx];
        __syncthreads();
#pragma unroll
        for (int r = 0; r < 32; r += 8)
            Wt[(size_t)(bxx + ty + r) * C_ + byy + tx] = (bf16)sh[tx * 33 + ty + r];
    } else if (bx < 2592) {
        int p = bx - 2576;                   // k-slice [32p, 32p+32)
#pragma unroll
        for (int h = 0; h < 2; ++h) {
            int c = h * 256 + tid;
            float s = 0.f;
#pragma unroll
            for (int kk = 0; kk < 32; ++kk) {
                int k = p * 32 + kk;
                s += b1[k] * W2[(size_t)k * C_ + c];
            }
            qpart[p * 512 + c] = s;
        }
    } else {
#pragma unroll
        for (int r = 0; r < 16; ++r) {
            int i = r * 256 + tid;           // [0,4096)
            out[(i >> 9) * 2 * C_ + C_ + (i & 511)] = 0.f;
        }
    }
}

// 128x128-tile NT GEMM: acc = A*B^T (+ sum of 16 qpart partials if OM==1).
// OM=0: C bf16, no bias.  OM=1: C fp8 e4m3 x16, K-permuted within 64-col blocks.
template <int OM>
__global__ __launch_bounds__(256) void gemm_nt(
    const bf16* __restrict__ A, size_t strideA,
    const bf16* __restrict__ Bm, size_t strideB,
    const float* __restrict__ qpart,
    void* __restrict__ Cv, size_t strideC,
    int N, int K) {
    __shared__ __attribute__((aligned(16))) bf16 lA[128 * 64];
    __shared__ __attribute__((aligned(16))) bf16 lB[128 * 64];
    const int tid = threadIdx.x;
    const int lane = tid & 63, w = tid >> 6;
    const int wm = w >> 1, wn = w & 1;
    const int z = blockIdx.z;
    const int bm = blockIdx.x * 128, bn = blockIdx.y * 128;
    const bf16* Ab = A + (size_t)z * strideA;
    const bf16* Bb = Bm + (size_t)z * strideB;

    f32x4 acc[4][4];
#pragma unroll
    for (int i = 0; i < 4; ++i)
#pragma unroll
        for (int j = 0; j < 4; ++j) acc[i][j] = f32x4{0.f, 0.f, 0.f, 0.f};

    const int nkt = K >> 6;
    for (int kt = 0; kt < nkt; ++kt) {
#pragma unroll
        for (int c = 0; c < 4; ++c) {
            int ca = c * 256 + tid;
            int row = ca >> 3;
            int qd = (ca & 7) ^ (row & 7);
            gload_lds16(Ab + (size_t)(bm + row) * K + kt * 64 + qd * 8,
                        lA + c * 2048 + w * 512);
            gload_lds16(Bb + (size_t)(bn + row) * K + kt * 64 + qd * 8,
                        lB + c * 2048 + w * 512);
        }
        __syncthreads();

        bf16x8 af[2][4], bfr[2][4];
#pragma unroll
        for (int ks = 0; ks < 2; ++ks) {
            int y = ks * 4 + (lane >> 4);
#pragma unroll
            for (int i = 0; i < 4; ++i) {
                int ra = wm * 64 + i * 16 + (lane & 15);
                int rb = wn * 64 + i * 16 + (lane & 15);
                af[ks][i]  = *(const bf16x8*)&lA[ra * 64 + ((y ^ (ra & 7)) * 8)];
                bfr[ks][i] = *(const bf16x8*)&lB[rb * 64 + ((y ^ (rb & 7)) * 8)];
            }
        }
#pragma unroll
        for (int ks = 0; ks < 2; ++ks)
#pragma unroll
            for (int i = 0; i < 4; ++i)
#pragma unroll
                for (int j = 0; j < 4; ++j)
                    acc[i][j] = __builtin_amdgcn_mfma_f32_16x16x32_bf16(
                        af[ks][i], bfr[ks][j], acc[i][j], 0, 0, 0);
        __syncthreads();
    }

    float bvj[4];
#pragma unroll
    for (int j = 0; j < 4; ++j) {
        bvj[j] = 0.f;
        if constexpr (OM == 1) {
            int col = bn + wn * 64 + j * 16 + (lane & 15);
#pragma unroll
            for (int p = 0; p < 16; ++p) bvj[j] += qpart[p * 512 + col];
        }
    }
#pragma unroll
    for (int i = 0; i < 4; ++i) {
#pragma unroll
        for (int j = 0; j < 4; ++j) {
            int col = bn + wn * 64 + j * 16 + (lane & 15);
#pragma unroll
            for (int r = 0; r < 4; ++r) {
                int row = bm + wm * 64 + i * 16 + (lane >> 4) * 4 + r;
                float v = acc[i][j][r] + bvj[j];
                if constexpr (OM == 0) {
                    ((bf16*)Cv)[(size_t)z * strideC + (size_t)row * N + col] = (bf16)v;
                } else {
                    int m = lane & 15;
                    int colp = (col & ~63) + ((2 * j + (m >> 3)) & 3) * 16 +
                               (j >> 1) * 8 + (m & 7);
                    ((unsigned char*)Cv)[(size_t)z * strideC + (size_t)row * N + colp] =
                        f32_to_fp8(v * 16.0f);
                }
            }
        }
    }
}

// ---- P-GEMM (fp8): 256^2 tile, 16 waves, 64x64/wave. K-permuted operands ->
// one ds_read_b128 per fragment-pair, stage/read XOR slot^(row&3).
// m97-idiom loop, vmcnt(2), 2 barriers/K-tile.
// P[z] = fp8( exp(min((A@B^T)/16, 8.8)) * 2^-4 ).
__global__ __launch_bounds__(1024, 4) void gemm256w(
    const unsigned char* __restrict__ A, const unsigned char* __restrict__ Bm,
    unsigned char* __restrict__ P) {
    __shared__ __attribute__((aligned(16))) unsigned char ls[2][2][16384]; // 64 KiB
    const int tid = threadIdx.x;
    const int lane = tid & 63, w = tid >> 6;
    const int wm = w >> 2, wn = w & 3;          // 4 x 4 waves, 64x64 each
    const int q4 = lane >> 4;                    // lane's 16B slot id (0..3)
    const int id = blockIdx.x;
    const int sw = (id & 7) * 64 + (id >> 3);   // batch z == XCD
    const int z = sw >> 6, tt = sw & 63;
    const int bm = (tt >> 3) * 256, bn = (tt & 7) * 256;
    const unsigned char* Ab = A + (size_t)z * N_ * C_;
    const unsigned char* Bb = Bm + (size_t)z * N_ * C_;

    f32x4 acc[4][4];
#pragma unroll
    for (int i = 0; i < 4; ++i)
#pragma unroll
        for (int j = 0; j < 4; ++j) acc[i][j] = f32x4{0.f, 0.f, 0.f, 0.f};

#define STAGE_T(kt_, buf_)                                                        \
    {                                                                             \
        int row = tid >> 2;                                                       \
        int qd = (tid & 3) ^ (row & 3);                                           \
        gload_lds16(Ab + (size_t)(bm + row) * 512 + (kt_) * 64 + qd * 16,         \
                    &ls[buf_][0][w * 1024]);                                      \
        gload_lds16(Bb + (size_t)(bn + row) * 512 + (kt_) * 64 + qd * 16,         \
                    &ls[buf_][1][w * 1024]);                                      \
    }

    STAGE_T(0, 0);
    STAGE_T(1, 1);
    asm volatile("s_waitcnt vmcnt(2)" ::: "memory");   // T0 landed; T1 in flight
    __builtin_amdgcn_s_barrier();
    asm volatile("" ::: "memory");

#pragma unroll
    for (int j = 0; j < 8; ++j) {
        const int cur = j & 1;
        const unsigned char* lA = &ls[cur][0][0];
        const unsigned char* lB = &ls[cur][1][0];

        long af[4][2], bfv[4][2];
#pragma unroll
        for (int i = 0; i < 4; ++i) {
            int ra = wm * 64 + i * 16 + (lane & 15);
            longx2 t = *(const longx2*)&lA[ra * 64 + ((q4 ^ (ra & 3)) * 16)];
            af[i][0] = t[0]; af[i][1] = t[1];
        }
#pragma unroll
        for (int jj = 0; jj < 4; ++jj) {
            int rb = wn * 64 + jj * 16 + (lane & 15);
            longx2 t = *(const longx2*)&lB[rb * 64 + ((q4 ^ (rb & 3)) * 16)];
            bfv[jj][0] = t[0]; bfv[jj][1] = t[1];
        }
        __builtin_amdgcn_s_setprio(1);
#pragma unroll
        for (int ks = 0; ks < 2; ++ks)
#pragma unroll
            for (int i = 0; i < 4; ++i)
#pragma unroll
                for (int jj = 0; jj < 4; ++jj)
                    acc[i][jj] = __builtin_amdgcn_mfma_f32_16x16x32_fp8_fp8(
                        af[i][ks], bfv[jj][ks], acc[i][jj], 0, 0, 0);
        __builtin_amdgcn_s_setprio(0);

        asm volatile("" ::: "memory");
        __builtin_amdgcn_s_barrier();
        asm volatile("" ::: "memory");

        if (j + 2 < 8) STAGE_T(j + 2, cur);
        if (j < 7) {
            if (j < 6) asm volatile("s_waitcnt vmcnt(2)" ::: "memory"); // T_{j+1} landed
            else       asm volatile("s_waitcnt vmcnt(0)" ::: "memory"); // T7 landed
            __builtin_amdgcn_s_barrier();               // publish T_{j+1}
            asm volatile("" ::: "memory");
        }
    }

    unsigned char* Pb = P + (size_t)z * N_ * N_;
#pragma unroll
    for (int fi = 0; fi < 4; ++fi) {
#pragma unroll
        for (int fj = 0; fj < 4; ++fj) {
            int col = bn + wn * 64 + fj * 16 + (lane & 15);
#pragma unroll
            for (int r = 0; r < 4; ++r) {
                int row = bm + wm * 64 + fi * 16 + (lane >> 4) * 4 + r;
                float v = __expf(fminf(acc[fi][fj][r] * 0.0625f, 8.8f)) * 0.0625f;
                Pb[(size_t)row * N_ + col] = f32_to_fp8(v);
            }
        }
    }
#undef STAGE_T
}

// Single-read softmax column-sums over fp8 P: block (s,b) owns 32 rows x 2048
// cols. wpart[b][s][j] plain-stored (s in [0,64)).
__global__ __launch_bounds__(256) void k_w2(const unsigned char* __restrict__ P,
                                            float* __restrict__ wpart) {
    __shared__ float rp[32 * 256];   // 32 KB
    __shared__ float ri[32];
    const int tid = threadIdx.x;
    const int s = blockIdx.x, b = blockIdx.y;
    const unsigned char* Pb = P + (size_t)b * N_ * N_ + (size_t)s * 32 * N_;
    const int j0 = tid * 8;
    uint2 v[32];
#pragma unroll
    for (int r = 0; r < 32; ++r) {
        v[r] = *(const uint2*)&Pb[(size_t)r * N_ + j0];
        float f[8];
        fp8x4_to_f32(v[r].x, &f[0]);
        fp8x4_to_f32(v[r].y, &f[4]);
        float t = 0.f;
#pragma unroll
        for (int e = 0; e < 8; ++e) t += f[e];
        rp[r * 256 + tid] = t;
    }
    __syncthreads();
    {
        int row = tid >> 3, seg = tid & 7;   // 32 rows x 8 segs
        float t = 0.f;
#pragma unroll
        for (int k = 0; k < 32; ++k) t += rp[row * 256 + seg + 8 * k];
#pragma unroll
        for (int m = 4; m; m >>= 1) t += __shfl_xor(t, m);
        if (seg == 0) ri[row] = 1.0f / t;
    }
    __syncthreads();
    float acc8[8] = {0.f, 0.f, 0.f, 0.f, 0.f, 0.f, 0.f, 0.f};
#pragma unroll
    for (int r = 0; r < 32; ++r) {
        float rr = ri[r];
        float f[8];
        fp8x4_to_f32(v[r].x, &f[0]);
        fp8x4_to_f32(v[r].y, &f[4]);
#pragma unroll
        for (int e = 0; e < 8; ++e) acc8[e] += rr * f[e];
    }
    float* wp = wpart + ((size_t)b * 64 + s) * (size_t)N_;
#pragma unroll
    for (int e = 0; e < 8; ++e) wp[j0 + e] = acc8[e];
}

// Block (slab,b): w[j] = 1 + sum_s wpart[b][s][j] for 256 j's, then atomicAdd
// (1/N) * sum_j w[j]*nodes_f8[b][j][:] into out's gp region (zeroed by k_prep).
__global__ __launch_bounds__(256) void k_gp(const unsigned char* __restrict__ nodes_f8,
                                            const float* __restrict__ wpart,
                                            float* __restrict__ out) {
    __shared__ float wsh[256];
    __shared__ float gred[4][512];
    const int tid = threadIdx.x;
    const int slab = blockIdx.x, b = blockIdx.y;
    const int j0 = slab * 256;
    {
        float wacc = 1.0f;
        for (int s = 0; s < 64; ++s)
            wacc += wpart[((size_t)b * 64 + s) * N_ + j0 + tid];
        wsh[tid] = wacc;
    }
    __syncthreads();
    const int cc = (tid & 63) * 8, jr = tid >> 6;
    const int lc = (cc & ~63) + ((cc >> 3) & 1) * 32 + ((cc >> 4) & 3) * 8;
    const unsigned char* nb = nodes_f8 + (size_t)b * N_ * C_;
    float acc8[8] = {0.f, 0.f, 0.f, 0.f, 0.f, 0.f, 0.f, 0.f};
    for (int j = jr; j < 256; j += 4) {
        float wj = wsh[j];
        uint2 nv = *(const uint2*)&nb[(size_t)(j0 + j) * C_ + cc];
        float f[8];
        fp8x4_to_f32(nv.x, &f[0]);
        fp8x4_to_f32(nv.y, &f[4]);
#pragma unroll
        for (int e = 0; e < 8; ++e) acc8[e] += wj * f[e];
    }
#pragma unroll
    for (int e = 0; e < 8; ++e) gred[jr][lc + e] = acc8[e];
    __syncthreads();
    if (tid < 64) {
#pragma unroll
        for (int e = 0; e < 8; ++e) {
            int c = tid * 8 + e;
            float s = gred[0][c] + gred[1][c] + gred[2][c] + gred[3][c];
            atomicAdd(&out[b * 2 * C_ + C_ + c], s * (1.0f / N_));
        }
    }
}

extern "C" void kernel_launch(void* const* d_in, const int* in_sizes, int n_in,
                              void* d_out, int out_size, void* d_ws, size_t ws_size,
                              hipStream_t stream) {
    const float* vd_s  = (const float*)d_in[0];
    const float* nodes = (const float*)d_in[1];
    const float* W1    = (const float*)d_in[2];
    const float* b1    = (const float*)d_in[3];
    const float* W2    = (const float*)d_in[4];
    // d_in[5] (b2) adds a row-constant to adj -> cancels in row-softmax -> unused
    float* out = (float*)d_out;

    char* ws = (char*)d_ws;
    bf16*          nodes_bf = (bf16*)(ws);                            // 16 MB
    unsigned char* H2f8     = (unsigned char*)(ws + ((size_t)16 << 20)); // 8 MB
    float*         wpart    = (float*)(ws + ((size_t)16 << 20));      // 4 MB, overlays
                                                                      // H2f8 (dead after P-GEMM)
    unsigned char* nodes_f8 = (unsigned char*)(ws + ((size_t)24 << 20)); // 8 MB
    unsigned char* P        = (unsigned char*)(ws + ((size_t)32 << 20)); // 32 MB (fp8)
    bf16*          W1t      = (bf16*)(ws + ((size_t)96 << 20));       // 512 KB
    bf16*          W2t      = (bf16*)(ws + ((size_t)96 << 20) + (512u << 10));
    bf16*          Gt       = (bf16*)(ws + ((size_t)96 << 20) + (1024u << 10));
    float*         qpart    = (float*)(ws + ((size_t)96 << 20) + (1536u << 10)); // 32 KB

    k_prep<<<2593, 256, 0, stream>>>(vd_s, nodes, W1, W2, b1,
                                     out, nodes_bf, nodes_f8, W1t, W2t, qpart);

    // Gt[c][k] = sum_m W2t[c][m]*W1t[k][m]   (bf16 out)
    gemm_nt<0><<<dim3(4, 4, 1), 256, 0, stream>>>(
        W2t, 0, W1t, 0, nullptr, Gt, 0, C_, C_);
    // H2f8[b] = fp8( 16 * (nodes_bf[b] @ Gt^T + q[col]) ), K-permuted cols
    gemm_nt<1><<<dim3(16, 4, 8), 256, 0, stream>>>(
        nodes_bf, (size_t)N_ * C_, Gt, 0, qpart,
        H2f8, (size_t)N_ * C_, C_, C_);
    // P[b] = fp8( exp((H2f8[b] @ nodes_f8[b]^T)/16) * 2^-4 )
    gemm256w<<<512, 1024, 0, stream>>>(H2f8, nodes_f8, P);

    k_w2<<<dim3(64, 8), 256, 0, stream>>>(P, wpart);
    k_gp<<<dim3(8, 8), 256, 0, stream>>>(nodes_f8, wpart, out);
}